// Round 11
// baseline (69.887 us; speedup 1.0000x reference)
//
#include <hip/hip_runtime.h>

#define N_IN 2048
#define N_HID 8192
#define N_OUT 1024
#define NTOT 11264

typedef __attribute__((ext_vector_type(4))) float f32x4;
typedef __attribute__((ext_vector_type(4))) short short4v;
typedef __attribute__((ext_vector_type(8))) short short8v;
typedef __attribute__((ext_vector_type(2))) unsigned u32x2;

// f32 -> bf16 RNE (scalar, epilogue only)
__device__ inline short f2bf(float f) {
    unsigned u = __float_as_uint(f);
    return (short)((u + 0x7fffu + ((u >> 16) & 1u)) >> 16);
}

__device__ inline float bf2f(short s) {
    return __uint_as_float(((unsigned)(unsigned short)s) << 16);
}

// packed f32x2 -> bf16x2 (hardware RNE)
__device__ inline unsigned cvt_pk_bf16(float lo, float hi) {
    unsigned r;
    asm("v_cvt_pk_bf16_f32 %0, %1, %2" : "=v"(r) : "v"(lo), "v"(hi));
    return r;
}

// k-interleave within 64-wide K group: lane's 8 MFMA operand values contiguous.
__device__ inline int perm64(int c) {
    return (c & 32) + (((c >> 2) & 3) << 3) + (((c >> 4) & 1) << 2) + (c & 3);
}

__device__ inline void gload_lds16(const void* g, void* l) {
    __builtin_amdgcn_global_load_lds(
        (const __attribute__((address_space(1))) unsigned int*)g,
        (__attribute__((address_space(3))) unsigned int*)l, 16, 0, 0);
}

// ---------------------------------------------------------------------------
// x (f32) -> xb (bf16, k-interleaved), 512x2048
// ---------------------------------------------------------------------------
__global__ __launch_bounds__(256) void cvt_x(
    const float* __restrict__ x, short* __restrict__ xb)
{
    const int i = blockIdx.x * 256 + threadIdx.x;   // grid 1024
    const f32x4 v = *reinterpret_cast<const f32x4*>(x + (size_t)i * 4);
    u32x2 s;
    s[0] = cvt_pk_bf16(v[0], v[1]);
    s[1] = cvt_pk_bf16(v[2], v[3]);
    const int c0  = (i * 4) & (N_IN - 1);
    const int p   = (c0 & ~63) + perm64(c0 & 63);
    const size_t row = (size_t)(i >> 9);
    *reinterpret_cast<u32x2*>(xb + row * N_IN + p) = s;
}

// ---------------------------------------------------------------------------
// Unified GEMM, BK=128 per barrier period (2x 64-k subtiles), strict counted
// vmcnt: per iter queue [B(T+1) | A(T+1) | B(T+2)], WAITV(12) then WAITV(8)
// before the barrier (cross-wave DMA-safe). 8 waves (2 row x 4 col), acc 4x2,
// 128x128 tile. LDS = As 2x32KB + Bs 2x36KB = 136 KB.
// ---------------------------------------------------------------------------
template<bool FUSE>
__global__ __launch_bounds__(512, 2) void gemm_bf16(
    const short* __restrict__ A,
    const float* __restrict__ W,
    const float* __restrict__ bias,
    short* __restrict__ hOut,
    short* __restrict__ pOut,       // !FUSE: bf16 split-K partials
    int lda, int nt, int wrow0, int wcol0)   // nt = # of 128-k big tiles
{
    __shared__ __align__(16) short As[2][128 * 128];       // 64 KB (2 subtiles)
    __shared__ __align__(16) short Bs[2][2 * 128 * 72];    // 72 KB (2 subtiles)

    const int t    = threadIdx.x;
    const int lane = t & 63;
    const int wid  = t >> 6;
    const int wr   = wid >> 2;
    const int wc   = wid & 3;
    const int brow = blockIdx.y * 128;
    const int bcol = blockIdx.x * 128;
    const int l15  = lane & 15;
    const int lg   = lane >> 4;
    const int ks   = blockIdx.z * 1024;

    const int arow = lane >> 3;
    const int asw  = ((lane & 7) * 16) ^ (arow << 4);

    const int nb   = (lane & 7) + 8 * (wid >> 1);
    const int kblk = ((lane >> 3) & 7) + 8 * (wid & 1);
    const int n0 = nb * 4, k0 = kblk * 4;
    const int p0 = perm64(k0);

    const char*  Abytes = (const char*)A;
    const size_t lda_b  = (size_t)lda * 2;

    // per-lane global A bases; big tile stride = 256 B, subtile 1 at +128 B
    const char* aG0 = Abytes + (size_t)(brow + (wid * 2 + 0) * 8 + arow) * lda_b
                             + (size_t)ks * 2 + asw;
    const char* aG1 = Abytes + (size_t)(brow + (wid * 2 + 1) * 8 + arow) * lda_b
                             + (size_t)ks * 2 + asw;
    const int ldsAoff = wid * 2048;

    f32x4 acc[4][2] = {};
    f32x4 bvE[8], bvO[8];

    const float* wp0 = &W[(size_t)(wrow0 + ks + k0) * NTOT + (wcol0 + bcol + n0)];

// 8 loads: rows k0+{0..3} (sub0) and k0+64+{0..3} (sub1)
#define B_LOAD(TT, BV) { \
    const float* wp = wp0 + (size_t)(TT) * 128 * NTOT; \
    _Pragma("unroll") for (int j = 0; j < 4; ++j) \
        BV[j] = *reinterpret_cast<const f32x4*>(wp + (size_t)j * NTOT); \
    _Pragma("unroll") for (int j = 4; j < 8; ++j) \
        BV[j] = *reinterpret_cast<const f32x4*>(wp + (size_t)(j + 60) * NTOT); }

// 4 loads: 2 chunks x 2 subtiles into As[(TT)&1]
#define A_LOAD(TT) { \
    char* dst = (char*)As + ((TT) & 1) * 32768; \
    gload_lds16(aG0 + (size_t)(TT) * 256,       dst + ldsAoff); \
    gload_lds16(aG1 + (size_t)(TT) * 256,       dst + ldsAoff + 1024); \
    gload_lds16(aG0 + (size_t)(TT) * 256 + 128, dst + 16384 + ldsAoff); \
    gload_lds16(aG1 + (size_t)(TT) * 256 + 128, dst + 16384 + ldsAoff + 1024); }

// 8 ds_write_b64: both subtiles, stride-72 [n][perm k] layout
#define B_WRITE(TT, BV) { \
    char* bsb = (char*)Bs + ((TT) & 1) * 36864; \
    _Pragma("unroll") for (int i = 0; i < 4; ++i) { \
        u32x2 s0, s1; \
        s0[0] = cvt_pk_bf16(BV[0][i], BV[1][i]); \
        s0[1] = cvt_pk_bf16(BV[2][i], BV[3][i]); \
        s1[0] = cvt_pk_bf16(BV[4][i], BV[5][i]); \
        s1[1] = cvt_pk_bf16(BV[6][i], BV[7][i]); \
        *reinterpret_cast<u32x2*>(bsb + (n0 + i) * 144 + p0 * 2) = s0; \
        *reinterpret_cast<u32x2*>(bsb + 18432 + (n0 + i) * 144 + p0 * 2) = s1; } }

// 32 MFMA over 2 subtiles x 2 k-groups
#define COMPUTE(TT) { \
    _Pragma("unroll") for (int g2 = 0; g2 < 2; ++g2) { \
        const char* ab = (const char*)As + ((TT) & 1) * 32768 + g2 * 16384; \
        const char* bb = (const char*)Bs + ((TT) & 1) * 36864 + g2 * 18432; \
        short8v a[2][4], b[2][2]; \
        _Pragma("unroll") for (int g = 0; g < 2; ++g) { \
            const int koff = g * 64 + lg * 16; \
            _Pragma("unroll") for (int m = 0; m < 4; ++m) { \
                const int r = wr * 64 + m * 16 + l15; \
                a[g][m] = *reinterpret_cast<const short8v*>( \
                    ab + ((r * 128 + koff) ^ ((r & 7) << 4))); } \
            _Pragma("unroll") for (int n = 0; n < 2; ++n) { \
                const int r = wc * 32 + n * 16 + l15; \
                b[g][n] = *reinterpret_cast<const short8v*>( \
                    bb + r * 144 + koff); } } \
        __builtin_amdgcn_s_setprio(1); \
        _Pragma("unroll") for (int g = 0; g < 2; ++g) \
          _Pragma("unroll") for (int m = 0; m < 4; ++m) \
            _Pragma("unroll") for (int n = 0; n < 2; ++n) \
                acc[m][n] = __builtin_amdgcn_mfma_f32_16x16x32_bf16( \
                    a[g][m], b[g][n], acc[m][n], 0, 0, 0); \
        __builtin_amdgcn_s_setprio(0); } }

#define WAITV(N) { asm volatile("s_waitcnt vmcnt(" #N ")" ::: "memory"); \
                   __builtin_amdgcn_sched_barrier(0); }
#define BARRIER  { asm volatile("s_waitcnt lgkmcnt(0)" ::: "memory"); \
                   __builtin_amdgcn_sched_barrier(0); \
                   __builtin_amdgcn_s_barrier(); \
                   __builtin_amdgcn_sched_barrier(0); }

// Iter T: queue in [B(T+1)8]; out [B(T+2)8]. A(T+1) issued BEFORE B(T+2).
#define ITER(T, BVL, BVW) { \
    A_LOAD(T + 1); \
    B_LOAD(T + 2, BVL); \
    WAITV(12);              /* retire B(T+1) */ \
    B_WRITE(T + 1, BVW); \
    COMPUTE(T); \
    WAITV(8);               /* retire A(T+1): cross-wave safe after barrier */ \
    BARRIER; }

    // ---- prologue: queue [B0 8 | A0 4 | B1 8] ----
    B_LOAD(0, bvE);
    A_LOAD(0);
    B_LOAD(1, bvO);
    WAITV(8);                 // retire B0 + A0 (leaves B1)
    B_WRITE(0, bvE);
    BARRIER;

    // ---- main loop: iters T = 0 .. nt-3 (even count; nt even) ----
    for (int tt = 0; tt + 3 < nt; tt += 2) {
        ITER(tt,     bvE, bvO);   // loads B(tt+2)->bvE, writes B(tt+1) from bvO
        ITER(tt + 1, bvO, bvE);
    }

    // ---- tail: T = nt-2, nt-1 ----
    A_LOAD(nt - 1);
    WAITV(4);                 // retire B(nt-1)
    B_WRITE(nt - 1, bvO);     // nt even -> nt-1 odd -> bvO
    COMPUTE(nt - 2);
    WAITV(0);                 // retire A(nt-1) BEFORE barrier (cross-wave)
    BARRIER;
    COMPUTE(nt - 1);

#undef B_LOAD
#undef A_LOAD
#undef B_WRITE
#undef COMPUTE
#undef WAITV
#undef BARRIER
#undef ITER

    if (FUSE) {
#pragma unroll
        for (int m = 0; m < 4; ++m) {
            const int row0 = brow + wr * 64 + m * 16 + lg * 4;
#pragma unroll
            for (int n = 0; n < 2; ++n) {
                const int col  = bcol + wc * 32 + n * 16 + l15;
                const int pcol = (col & ~63) + perm64(col & 63);
                const float bb = bias[N_IN + col];
#pragma unroll
                for (int q = 0; q < 4; ++q) {
                    float v = acc[m][n][q] + bb;
                    v = v > 0.f ? v : 0.f;
                    hOut[(size_t)(row0 + q) * N_HID + pcol] = f2bf(v);
                }
            }
        }
    } else {
        short* po = pOut + (size_t)blockIdx.z * (512 * N_OUT);
#pragma unroll
        for (int m = 0; m < 4; ++m) {
            const int row0 = brow + wr * 64 + m * 16 + lg * 4;
#pragma unroll
            for (int n = 0; n < 2; ++n) {
                const int col = bcol + wc * 32 + n * 16 + l15;
#pragma unroll
                for (int q = 0; q < 4; ++q)
                    po[(size_t)(row0 + q) * N_OUT + col] = f2bf(acc[m][n][q]);
            }
        }
    }
}

// ---------------------------------------------------------------------------
// Reduce 8 bf16 split-K partials + output bias -> out (f32)
// ---------------------------------------------------------------------------
__global__ __launch_bounds__(256) void reduce_bias(
    const short* __restrict__ part,  // [8][512][1024] bf16
    const float* __restrict__ bias,
    float* __restrict__ out)         // [512][1024] f32
{
    const int idx = (blockIdx.x * 256 + threadIdx.x) * 4;  // grid 512
    f32x4 s = *reinterpret_cast<const f32x4*>(&bias[N_IN + N_HID + (idx & 1023)]);
#pragma unroll
    for (int sp = 0; sp < 8; ++sp) {
        const short4v p = *reinterpret_cast<const short4v*>(
            &part[(size_t)sp * 524288 + idx]);
#pragma unroll
        for (int j = 0; j < 4; ++j) s[j] += bf2f(p[j]);
    }
    *reinterpret_cast<f32x4*>(&out[idx]) = s;
}

extern "C" void kernel_launch(void* const* d_in, const int* in_sizes, int n_in,
                              void* d_out, int out_size, void* d_ws, size_t ws_size,
                              hipStream_t stream) {
    const float* x    = (const float*)d_in[0];
    const float* W    = (const float*)d_in[1];
    const float* bias = (const float*)d_in[2];
    // d_in[3] = mask: structurally fixed 3-level DAG, never read.
    float* out = (float*)d_out;

    // ws: h @0 (8 MiB bf16), part @8MiB (8 MiB bf16), xb aliases part
    short* h    = (short*)d_ws;
    short* part = (short*)((char*)d_ws + (size_t)(8 << 20));
    short* xb   = (short*)((char*)d_ws + (size_t)(8 << 20));  // dead before GEMM2

    cvt_x<<<dim3(1024), dim3(256), 0, stream>>>(x, xb);

    // GEMM1: H = relu(xb @ W[0:2048, 2048:10240] + b), M=512 N=8192 K=2048
    gemm_bf16<true><<<dim3(64, 4, 1), dim3(512), 0, stream>>>(
        xb, W, bias, h, nullptr, N_IN, 16, 0, N_IN);

    // GEMM2: part[z] = H[:, z*1024:+1024] @ W[2048+z*1024:+1024, 10240:11264]
    gemm_bf16<false><<<dim3(8, 4, 8), dim3(512), 0, stream>>>(
        h, W, nullptr, nullptr, part, N_HID, 8, N_IN, N_IN + N_HID);

    reduce_bias<<<dim3(512), dim3(256), 0, stream>>>(part, bias, out);
}

// Round 12
// 66.243 us; speedup vs baseline: 1.0550x; 1.0550x over previous
//
#include <hip/hip_runtime.h>

#define N_IN 2048
#define N_HID 8192
#define N_OUT 1024
#define NTOT 11264

typedef __attribute__((ext_vector_type(4))) float f32x4;
typedef __attribute__((ext_vector_type(4))) short short4v;
typedef __attribute__((ext_vector_type(8))) short short8v;
typedef __attribute__((ext_vector_type(2))) unsigned u32x2;

// f32 -> bf16 RNE (scalar, epilogue only)
__device__ inline short f2bf(float f) {
    unsigned u = __float_as_uint(f);
    return (short)((u + 0x7fffu + ((u >> 16) & 1u)) >> 16);
}

__device__ inline float bf2f(short s) {
    return __uint_as_float(((unsigned)(unsigned short)s) << 16);
}

// packed f32x2 -> bf16x2 (hardware RNE)
__device__ inline unsigned cvt_pk_bf16(float lo, float hi) {
    unsigned r;
    asm("v_cvt_pk_bf16_f32 %0, %1, %2" : "=v"(r) : "v"(lo), "v"(hi));
    return r;
}

// k-interleave within 64-wide K group: lane's 8 MFMA operand values contiguous.
__device__ inline int perm64(int c) {
    return (c & 32) + (((c >> 2) & 3) << 3) + (((c >> 4) & 1) << 2) + (c & 3);
}

__device__ inline void gload_lds16(const void* g, void* l) {
    __builtin_amdgcn_global_load_lds(
        (const __attribute__((address_space(1))) unsigned int*)g,
        (__attribute__((address_space(3))) unsigned int*)l, 16, 0, 0);
}

// ---------------------------------------------------------------------------
// x (f32) -> xb (bf16, k-interleaved), 512x2048
// ---------------------------------------------------------------------------
__global__ __launch_bounds__(256) void cvt_x(
    const float* __restrict__ x, short* __restrict__ xb)
{
    const int i = blockIdx.x * 256 + threadIdx.x;   // grid 1024
    const f32x4 v = *reinterpret_cast<const f32x4*>(x + (size_t)i * 4);
    u32x2 s;
    s[0] = cvt_pk_bf16(v[0], v[1]);
    s[1] = cvt_pk_bf16(v[2], v[3]);
    const int c0  = (i * 4) & (N_IN - 1);
    const int p   = (c0 & ~63) + perm64(c0 & 63);
    const size_t row = (size_t)(i >> 9);
    *reinterpret_cast<u32x2*>(xb + row * N_IN + p) = s;
}

// ---------------------------------------------------------------------------
// Unified GEMM, DEPTH-3 counted-vmcnt pipeline (R10-proven core) + XCD-aware
// block swizzle: all blocks sharing a B column-slice land on one XCD so its
// L2 serves the 4x duplicate reads (flat%8 == XCD model, m157/m192).
// 8 waves (2 row x 4 col), acc 4x2, 128x128 tile, BK=64.
// ---------------------------------------------------------------------------
template<bool FUSE>
__global__ __launch_bounds__(512, 2) void gemm_bf16(
    const short* __restrict__ A,
    const float* __restrict__ W,
    const float* __restrict__ bias,
    short* __restrict__ hOut,
    short* __restrict__ pOut,       // !FUSE: bf16 split-K partials
    int lda, int nt, int wrow0, int wcol0)
{
    __shared__ __align__(16) short As[4][128 * 64];  // ring of 4, XOR-swizzled
    __shared__ __align__(16) short Bs[2][128][72];   // [n][perm k], stride 72

    // ---- XCD-aware decomposition of the flat 256-block grid ----
    const int bid = blockIdx.x;
    const int xcd = bid & 7;
    const int j   = bid >> 3;        // 0..31
    int bx, by, bz;
    if (FUSE) {      // grid logical (64 x, 4 y): 4 y-partners share B-slice
        bx = xcd * 8 + (j >> 2);     // 0..63
        by = j & 3;                  // 0..3
        bz = 0;
    } else {         // grid logical (8 x, 4 y, 8 z): XCD owns one z split
        const int xz = xcd * 8 + (j >> 2);   // 0..63
        bx = xz & 7;                 // 0..7
        bz = xz >> 3;                // == xcd
        by = j & 3;                  // 0..3
    }

    const int t    = threadIdx.x;
    const int lane = t & 63;
    const int wid  = t >> 6;
    const int wr   = wid >> 2;
    const int wc   = wid & 3;
    const int brow = by * 128;
    const int bcol = bx * 128;
    const int l15  = lane & 15;
    const int lg   = lane >> 4;
    const int ks   = bz * 1024;

    const int arow = lane >> 3;
    const int asw  = ((lane & 7) * 16) ^ (arow << 4);

    const int nb   = (lane & 7) + 8 * (wid >> 1);
    const int kblk = ((lane >> 3) & 7) + 8 * (wid & 1);
    const int n0 = nb * 4, k0 = kblk * 4;
    const int p0 = perm64(k0);

    const char*  Abytes = (const char*)A;
    const size_t lda_b  = (size_t)lda * 2;

    f32x4 acc[4][2] = {};
    f32x4 bv0[4], bv1[4], bv2[4], bv3[4];

    const float* wp0 = &W[(size_t)(wrow0 + ks + k0) * NTOT + (wcol0 + bcol + n0)];

#define B_LOAD(TT, BV) { \
    const float* wp = wp0 + (size_t)(TT) * 64 * NTOT; \
    _Pragma("unroll") for (int jj = 0; jj < 4; ++jj) \
        BV[jj] = *reinterpret_cast<const f32x4*>(wp + (size_t)jj * NTOT); }

#define A_LOAD(TT) { \
    char* dst = (char*)As + ((TT) & 3) * 16384; \
    _Pragma("unroll") for (int i = 0; i < 2; ++i) { \
        const int c = wid * 2 + i; \
        gload_lds16(Abytes + (size_t)(brow + c * 8 + arow) * lda_b \
                          + (size_t)(ks + (TT) * 64) * 2 + asw, \
                    dst + c * 1024); } }

#define B_WRITE(TT, BV) { \
    short* bsb = &Bs[(TT) & 1][0][0]; \
    _Pragma("unroll") for (int i = 0; i < 4; ++i) { \
        u32x2 s; \
        s[0] = cvt_pk_bf16(BV[0][i], BV[1][i]); \
        s[1] = cvt_pk_bf16(BV[2][i], BV[3][i]); \
        *reinterpret_cast<u32x2*>(bsb + (n0 + i) * 72 + p0) = s; } }

#define COMPUTE(TT) { \
    const char*  ab = (const char*)As + ((TT) & 3) * 16384; \
    const short* bb = &Bs[(TT) & 1][0][0]; \
    short8v a[2][4], b[2][2]; \
    _Pragma("unroll") for (int g = 0; g < 2; ++g) { \
        const int koff = g * 64 + lg * 16; \
        _Pragma("unroll") for (int m = 0; m < 4; ++m) { \
            const int r = wr * 64 + m * 16 + l15; \
            a[g][m] = *reinterpret_cast<const short8v*>( \
                ab + ((r * 128 + koff) ^ ((r & 7) << 4))); } \
        _Pragma("unroll") for (int n = 0; n < 2; ++n) { \
            const int r = wc * 32 + n * 16 + l15; \
            b[g][n] = *reinterpret_cast<const short8v*>( \
                (const char*)(bb + r * 72) + koff); } } \
    __builtin_amdgcn_s_setprio(1); \
    _Pragma("unroll") for (int g = 0; g < 2; ++g) \
      _Pragma("unroll") for (int m = 0; m < 4; ++m) \
        _Pragma("unroll") for (int n = 0; n < 2; ++n) \
            acc[m][n] = __builtin_amdgcn_mfma_f32_16x16x32_bf16( \
                a[g][m], b[g][n], acc[m][n], 0, 0, 0); \
    __builtin_amdgcn_s_setprio(0); }

#define WAITV(N) { asm volatile("s_waitcnt vmcnt(" #N ")" ::: "memory"); \
                   __builtin_amdgcn_sched_barrier(0); }
#define BARRIER  { asm volatile("s_waitcnt lgkmcnt(0)" ::: "memory"); \
                   __builtin_amdgcn_sched_barrier(0); \
                   __builtin_amdgcn_s_barrier(); \
                   __builtin_amdgcn_sched_barrier(0); }

// One steady-state iteration: process T; issue T+3; retire through T+1.
#define ITER(T, BVL, BVW) { \
    B_LOAD(T + 3, BVL); A_LOAD(T + 3); \
    WAITV(12); \
    B_WRITE(T + 1, BVW); \
    COMPUTE(T); \
    BARRIER; }

    // ---- prologue: tiles 0,1,2 in flight (18 loads) ----
    B_LOAD(0, bv0); A_LOAD(0);
    B_LOAD(1, bv1); A_LOAD(1);
    B_LOAD(2, bv2); A_LOAD(2);
    WAITV(12);                // tile 0 landed (1,2 still in flight)
    B_WRITE(0, bv0);
    BARRIER;

    // ---- main loop: processes 0 .. nt-5 (nt % 4 == 0) ----
    for (int tt = 0; tt + 4 < nt; tt += 4) {
        ITER(tt,     bv3, bv1);
        ITER(tt + 1, bv0, bv2);
        ITER(tt + 2, bv1, bv3);
        ITER(tt + 3, bv2, bv0);
    }
    // ---- last full iteration: processes nt-4, issues nt-1 ----
    ITER(nt - 4, bv3, bv1);

    // ---- tail: tiles nt-3, nt-2, nt-1 (all loads issued) ----
    WAITV(6);                 // tile nt-2 landed
    B_WRITE(nt - 2, bv2);
    COMPUTE(nt - 3);
    BARRIER;
    WAITV(0);                 // tile nt-1 landed
    B_WRITE(nt - 1, bv3);
    COMPUTE(nt - 2);
    BARRIER;
    COMPUTE(nt - 1);

#undef B_LOAD
#undef A_LOAD
#undef B_WRITE
#undef COMPUTE
#undef WAITV
#undef BARRIER
#undef ITER

    if (FUSE) {
#pragma unroll
        for (int m = 0; m < 4; ++m) {
            const int row0 = brow + wr * 64 + m * 16 + lg * 4;
#pragma unroll
            for (int n = 0; n < 2; ++n) {
                const int col  = bcol + wc * 32 + n * 16 + l15;
                const int pcol = (col & ~63) + perm64(col & 63);
                const float bb = bias[N_IN + col];
#pragma unroll
                for (int q = 0; q < 4; ++q) {
                    float v = acc[m][n][q] + bb;
                    v = v > 0.f ? v : 0.f;
                    hOut[(size_t)(row0 + q) * N_HID + pcol] = f2bf(v);
                }
            }
        }
    } else {
        short* po = pOut + (size_t)bz * (512 * N_OUT);
#pragma unroll
        for (int m = 0; m < 4; ++m) {
            const int row0 = brow + wr * 64 + m * 16 + lg * 4;
#pragma unroll
            for (int n = 0; n < 2; ++n) {
                const int col = bcol + wc * 32 + n * 16 + l15;
#pragma unroll
                for (int q = 0; q < 4; ++q)
                    po[(size_t)(row0 + q) * N_OUT + col] = f2bf(acc[m][n][q]);
            }
        }
    }
}

// ---------------------------------------------------------------------------
// Reduce 8 bf16 split-K partials + output bias -> out (f32)
// ---------------------------------------------------------------------------
__global__ __launch_bounds__(256) void reduce_bias(
    const short* __restrict__ part,  // [8][512][1024] bf16
    const float* __restrict__ bias,
    float* __restrict__ out)         // [512][1024] f32
{
    const int idx = (blockIdx.x * 256 + threadIdx.x) * 4;  // grid 512
    f32x4 s = *reinterpret_cast<const f32x4*>(&bias[N_IN + N_HID + (idx & 1023)]);
#pragma unroll
    for (int sp = 0; sp < 8; ++sp) {
        const short4v p = *reinterpret_cast<const short4v*>(
            &part[(size_t)sp * 524288 + idx]);
#pragma unroll
        for (int jj = 0; jj < 4; ++jj) s[jj] += bf2f(p[jj]);
    }
    *reinterpret_cast<f32x4*>(&out[idx]) = s;
}

extern "C" void kernel_launch(void* const* d_in, const int* in_sizes, int n_in,
                              void* d_out, int out_size, void* d_ws, size_t ws_size,
                              hipStream_t stream) {
    const float* x    = (const float*)d_in[0];
    const float* W    = (const float*)d_in[1];
    const float* bias = (const float*)d_in[2];
    // d_in[3] = mask: structurally fixed 3-level DAG, never read.
    float* out = (float*)d_out;

    // ws: h @0 (8 MiB bf16), part @8MiB (8 MiB bf16), xb aliases part
    short* h    = (short*)d_ws;
    short* part = (short*)((char*)d_ws + (size_t)(8 << 20));
    short* xb   = (short*)((char*)d_ws + (size_t)(8 << 20));  // dead before GEMM2

    cvt_x<<<dim3(1024), dim3(256), 0, stream>>>(x, xb);

    // GEMM1: H = relu(xb @ W[0:2048, 2048:10240] + b), M=512 N=8192 K=2048
    // flat 256-block grid, XCD-swizzled in-kernel
    gemm_bf16<true><<<dim3(256), dim3(512), 0, stream>>>(
        xb, W, bias, h, nullptr, N_IN, 32, 0, N_IN);

    // GEMM2: part[z] = H[:, z*1024:+1024] @ W[2048+z*1024:+1024, 10240:11264]
    gemm_bf16<false><<<dim3(256), dim3(512), 0, stream>>>(
        h, W, nullptr, nullptr, part, N_HID, 16, N_IN, N_IN + N_HID);

    reduce_bias<<<dim3(512), dim3(256), 0, stream>>>(part, bias, out);
}